// Round 9
// baseline (146.588 us; speedup 1.0000x reference)
//
#include <hip/hip_runtime.h>
#include <math.h>

// Chamfer loss, B=4, C=3, Np=Ng=8192, fp32 — MFMA 32x32x16 single-pass.
// R8 proved the 16-slot hi/lo bf16 packing of d2 = p2 + g2 - 2p.g is exact
// to absmax 0. R9 right-sizes the machine around it:
//  - mfma_f32_32x32x16_bf16: K=16 exactly fits the packing (R8 wasted half
//    its K=32 on zeros); one inst = 1024 pairs.
//  - A/B fragments: lane needs one contiguous 16-B half of a point's 32-B
//    slot vector -> two contiguous half-planes in LDS (16-B stride =
//    conflict-free for b128).
//  - NO LDS atomics in the main loop: col-min = in-register min3 tree +
//    shfl_xor(32) + plain per-wave ds_write; row-min in registers, folded
//    once at the end via LDS atomicMin.
//  - 33 KB LDS, launch_bounds(256,4) -> 4 blocks/CU, 16 waves/CU.
// Layouts: A[m=lane&31][k=(lane>>5)*8+j], B[k=(lane>>5)*8+j][n=lane&31],
// D: col=lane&31, row=(reg&3)+8*(reg>>2)+4*(lane>>5)  (m74/m101).
// Combine: R6 poison-ticket (0xAA ws poison = +inf for uint-min, ticket base).

#define B_        4
#define N_        8192
#define THREADS   256
#define ROWS_PB   256                 // 4 waves * 2 rowtiles * 32
#define ROWBLKS   (N_ / ROWS_PB)      // 32
#define MRANGE    512
#define MSPLIT    (N_ / MRANGE)       // 16
#define MTILES    (MRANGE / 32)       // 16
#define BLKS_PER_GROUP (ROWBLKS * MSPLIT)   // 512
#define POISON    0xAAAAAAAAu
#define INF_BITS  0x7F800000u

typedef __bf16 bf16x8 __attribute__((ext_vector_type(8)));
typedef float  f32x16 __attribute__((ext_vector_type(16)));

// LDS layout (bytes):
//   SM_A:   2 half-planes * 256 rows * 16 B = 8192
//   SM_B:   2 half-planes * 512 pts  * 16 B = 16384
//   SM_COL: 4 waves * 512 m * 4 B            = 8192   (float)
//   SM_ROW: 256 * 4 B                        = 1024   (uint)
#define SM_A      0
#define SM_B      8192
#define SM_COL    24576
#define SM_ROW    32768
#define SM_BYTES  33792

__device__ __forceinline__ unsigned short bf16_rne(float f) {
    unsigned u = __float_as_uint(f);
    return (unsigned short)((u + 0x7FFFu + ((u >> 16) & 1u)) >> 16);
}
__device__ __forceinline__ float bf16_tof(unsigned short h) {
    return __uint_as_float(((unsigned)h) << 16);
}

// A-side (predict) 16 slots — identical numerics to R8 (validated absmax 0)
__device__ __forceinline__ void slotsA(const float* base, int n, unsigned short* dst) {
    float x = base[n], y = base[N_ + n], z = base[2 * N_ + n];
    float p2 = fmaf(x, x, fmaf(y, y, z * z));
    unsigned short hx = bf16_rne(x), hy = bf16_rne(y), hz = bf16_rne(z);
    float lxf = x - bf16_tof(hx), lyf = y - bf16_tof(hy), lzf = z - bf16_tof(hz);
    unsigned short mhx = bf16_rne(-2.0f * bf16_tof(hx));
    unsigned short mhy = bf16_rne(-2.0f * bf16_tof(hy));
    unsigned short mhz = bf16_rne(-2.0f * bf16_tof(hz));
    unsigned short mlx = bf16_rne(-2.0f * bf16_tof(bf16_rne(lxf)));
    unsigned short mly = bf16_rne(-2.0f * bf16_tof(bf16_rne(lyf)));
    unsigned short mlz = bf16_rne(-2.0f * bf16_tof(bf16_rne(lzf)));
    unsigned short p2h = bf16_rne(p2);
    unsigned short p2l = bf16_rne(p2 - bf16_tof(p2h));
    const unsigned short ONE = 0x3F80;
    dst[0] = mhx;  dst[1] = mhy;  dst[2] = mhz;
    dst[3] = mhx;  dst[4] = mhy;  dst[5] = mhz;
    dst[6] = mlx;  dst[7] = mly;  dst[8] = mlz;
    dst[9] = p2h;  dst[10] = p2l; dst[11] = ONE; dst[12] = ONE;
    dst[13] = mlx; dst[14] = mly; dst[15] = mlz;
}

// B-side (gt) 16 slots
__device__ __forceinline__ void slotsB(const float* base, int m, unsigned short* dst) {
    float x = base[m], y = base[N_ + m], z = base[2 * N_ + m];
    float g2 = fmaf(x, x, fmaf(y, y, z * z));
    unsigned short hx = bf16_rne(x), hy = bf16_rne(y), hz = bf16_rne(z);
    unsigned short lx = bf16_rne(x - bf16_tof(hx));
    unsigned short ly = bf16_rne(y - bf16_tof(hy));
    unsigned short lz = bf16_rne(z - bf16_tof(hz));
    unsigned short g2h = bf16_rne(g2);
    unsigned short g2l = bf16_rne(g2 - bf16_tof(g2h));
    const unsigned short ONE = 0x3F80;
    dst[0] = hx;  dst[1] = hy;  dst[2] = hz;
    dst[3] = lx;  dst[4] = ly;  dst[5] = lz;
    dst[6] = hx;  dst[7] = hy;  dst[8] = hz;
    dst[9] = ONE; dst[10] = ONE; dst[11] = g2h; dst[12] = g2l;
    dst[13] = lx; dst[14] = ly; dst[15] = lz;
}

__device__ __forceinline__ float min16(const f32x16& a) {
    float c0 = fminf(fminf(a[0],  a[1]),  a[2]);
    float c1 = fminf(fminf(a[3],  a[4]),  a[5]);
    float c2 = fminf(fminf(a[6],  a[7]),  a[8]);
    float c3 = fminf(fminf(a[9],  a[10]), a[11]);
    float c4 = fminf(fminf(a[12], a[13]), a[14]);
    float c5 = fminf(fminf(c0, c1), a[15]);
    float c6 = fminf(fminf(c2, c3), c4);
    return fminf(c5, c6);
}

// ws (32-bit words):
//   [0, 32768)      predict-side mins [b][n]  (uint bits; poison = +inf)
//   [32768, 65536)  gt-side mins      [b][m]
//   [65536, 65540)  gcnt[4]   [65600] fcnt   [65664,65668) gsum[4]

__global__ __launch_bounds__(THREADS, 4)
void chamfer_mfma_kernel(const float* __restrict__ P, const float* __restrict__ G,
                         unsigned* __restrict__ mins, unsigned* __restrict__ gcnt,
                         unsigned* __restrict__ fcnt, float* __restrict__ gsum,
                         float* __restrict__ out)
{
    __shared__ __align__(16) char smem[SM_BYTES];
    __shared__ float red[THREADS];
    __shared__ unsigned s_ticket;

    const int t      = threadIdx.x;
    const int rowblk = blockIdx.x;     // 0..31
    const int mspl   = blockIdx.y;     // 0..15
    const int b      = blockIdx.z;     // 0..3
    const int rowbase = rowblk * ROWS_PB;
    const int mbase   = mspl * MRANGE;

    const float* Pb = P + (size_t)b * 3 * N_;
    const float* Gb = G + (size_t)b * 3 * N_;

    unsigned* rowmin = (unsigned*)(smem + SM_ROW);
    float*    colw   = (float*)(smem + SM_COL);

    // ---- stage: A (1 row/thread), B (2 pts/thread), rowmin init ----
    {
        unsigned short s[16];
        slotsA(Pb, rowbase + t, s);
        *(ulonglong2*)(smem + SM_A + t * 16)        = *(ulonglong2*)&s[0];  // k 0..7
        *(ulonglong2*)(smem + SM_A + 4096 + t * 16) = *(ulonglong2*)&s[8];  // k 8..15
#pragma unroll
        for (int k = 0; k < 2; ++k) {
            const int m = k * THREADS + t;
            slotsB(Gb, mbase + m, s);
            *(ulonglong2*)(smem + SM_B + m * 16)        = *(ulonglong2*)&s[0];
            *(ulonglong2*)(smem + SM_B + 8192 + m * 16) = *(ulonglong2*)&s[8];
        }
    }
    rowmin[t] = INF_BITS;
    __syncthreads();

    // ---- fragments ----
    const int lane = t & 63, wave = t >> 6;
    const int half = lane >> 5;        // which k-half this lane holds
    const int lrow = lane & 31;

    bf16x8 afrag[2];
#pragma unroll
    for (int rt = 0; rt < 2; ++rt)
        afrag[rt] = *(const bf16x8*)(smem + SM_A + half * 4096
                                     + (wave * 64 + rt * 32 + lrow) * 16);

    const char* bbase = smem + SM_B + half * 8192 + lrow * 16;

    f32x16 zero16 = {0.0f,0.0f,0.0f,0.0f,0.0f,0.0f,0.0f,0.0f,
                     0.0f,0.0f,0.0f,0.0f,0.0f,0.0f,0.0f,0.0f};
    float rmin0[16], rmin1[16];
#pragma unroll
    for (int r = 0; r < 16; ++r) { rmin0[r] = 3.4e38f; rmin1[r] = 3.4e38f; }

    // ---- main sweep: 16 m-tiles x (1 b128 + 2 MFMA + reg min-folds) ----
    for (int mt = 0; mt < MTILES; ++mt) {
        bf16x8 bfrag = *(const bf16x8*)(bbase + mt * 32 * 16);
        f32x16 acc0 = __builtin_amdgcn_mfma_f32_32x32x16_bf16(afrag[0], bfrag, zero16, 0, 0, 0);
        f32x16 acc1 = __builtin_amdgcn_mfma_f32_32x32x16_bf16(afrag[1], bfrag, zero16, 0, 0, 0);
#pragma unroll
        for (int r = 0; r < 16; ++r) {
            rmin0[r] = fminf(rmin0[r], acc0[r]);
            rmin1[r] = fminf(rmin1[r], acc1[r]);
        }
        float cp = fminf(min16(acc0), min16(acc1));   // all 16 share col=lane&31
        cp = fminf(cp, __shfl_xor(cp, 32, 64));       // fold the two row-halves
        if (lane < 32) colw[wave * MRANGE + mt * 32 + lrow] = cp;
    }

    // ---- row-side: registers -> LDS atomicMin (once per kernel) ----
#pragma unroll
    for (int r = 0; r < 16; ++r) {
        const int row0 = wave * 64 +      (r & 3) + 8 * (r >> 2) + 4 * half;
        const int row1 = wave * 64 + 32 + (r & 3) + 8 * (r >> 2) + 4 * half;
        atomicMin(&rowmin[row0], __float_as_uint(fmaxf(rmin0[r], 1e-12f)));
        atomicMin(&rowmin[row1], __float_as_uint(fmaxf(rmin1[r], 1e-12f)));
    }
    __syncthreads();   // all colw writes + rowmin atomics complete

    // ---- global flush ----
    atomicMin(&mins[(size_t)b * N_ + rowbase + t], rowmin[t]);
#pragma unroll
    for (int k = 0; k < 2; ++k) {
        const int m = k * THREADS + t;
        float cm = fminf(fminf(colw[m], colw[MRANGE + m]),
                         fminf(colw[2 * MRANGE + m], colw[3 * MRANGE + m]));
        atomicMin(&mins[32768 + (size_t)b * N_ + mbase + m],
                  __float_as_uint(fmaxf(cm, 1e-12f)));
    }

    // ---- per-batch ticket: last of 512 blocks finalizes batch b ----
    __syncthreads();               // barrier drains vmcnt: atomics done
    if (t == 0) {
        __threadfence();
        s_ticket = atomicAdd(&gcnt[b], 1u);
    }
    __syncthreads();
    if (s_ticket != POISON + (unsigned)(BLKS_PER_GROUP - 1)) return;

    // ---- batch leader: sqrt-sum both sides ----
    __threadfence();
    const uint4* v0 = (const uint4*)(mins + (size_t)b * N_);
    const uint4* v1 = (const uint4*)(mins + 32768 + (size_t)b * N_);
    float acc = 0.0f;
#pragma unroll
    for (int k = 0; k < N_ / 4 / THREADS; ++k) {   // 8
        uint4 q = v0[k * THREADS + t];
        uint4 w = v1[k * THREADS + t];
        acc += sqrtf(__uint_as_float(q.x)) + sqrtf(__uint_as_float(q.y))
             + sqrtf(__uint_as_float(q.z)) + sqrtf(__uint_as_float(q.w))
             + sqrtf(__uint_as_float(w.x)) + sqrtf(__uint_as_float(w.y))
             + sqrtf(__uint_as_float(w.z)) + sqrtf(__uint_as_float(w.w));
    }
    red[t] = acc;
    __syncthreads();
    for (int off = 128; off > 0; off >>= 1) {
        if (t < off) red[t] += red[t + off];
        __syncthreads();
    }
    if (t == 0) {
        gsum[b] = red[0];
        __threadfence();
        s_ticket = atomicAdd(fcnt, 1u);
    }
    __syncthreads();
    if (s_ticket != POISON + (unsigned)(B_ - 1)) return;

    __threadfence();
    if (t == 0)
        out[0] = (gsum[0] + gsum[1] + gsum[2] + gsum[3]) * (1.0f / 65536.0f);
}

extern "C" void kernel_launch(void* const* d_in, const int* in_sizes, int n_in,
                              void* d_out, int out_size, void* d_ws, size_t ws_size,
                              hipStream_t stream)
{
    const float* P = (const float*)d_in[0];   // predict_pc [4,3,8192]
    const float* G = (const float*)d_in[1];   // gt_pc      [4,3,8192]
    float* out = (float*)d_out;               // scalar

    unsigned* w    = (unsigned*)d_ws;
    unsigned* mins = w;                       // 65536 words
    unsigned* gcnt = w + 65536;               // 4 words
    unsigned* fcnt = w + 65600;               // 1 word
    float*    gsum = (float*)(w + 65664);     // 4 words

    dim3 grid(ROWBLKS, MSPLIT, B_);           // (32, 16, 4) = 2048 blocks
    chamfer_mfma_kernel<<<grid, THREADS, 0, stream>>>(P, G, mins, gcnt, fcnt, gsum, out);
}